// Round 9
// baseline (229.608 us; speedup 1.0000x reference)
//
#include <hip/hip_runtime.h>
#include <cstdint>

typedef unsigned short u16;
typedef __bf16 bf16x8 __attribute__((ext_vector_type(8)));
typedef float f32x4 __attribute__((ext_vector_type(4)));
typedef unsigned int u32x4 __attribute__((ext_vector_type(4)));

__device__ __forceinline__ float bf2f(u16 h) {
  union { unsigned int u; float f; } v; v.u = ((unsigned int)h) << 16; return v.f;
}
__device__ __forceinline__ u16 f2bf(float f) {
  union { float f; unsigned int u; } v; v.f = f;
  unsigned int u = v.u;
  return (u16)((u + 0x7FFFu + ((u >> 16) & 1u)) >> 16);  // RNE, finite inputs
}

__device__ __forceinline__ void ld_lds16(const void* g, void* l) {
  __builtin_amdgcn_global_load_lds(
      (const __attribute__((address_space(1))) unsigned int*)g,
      (__attribute__((address_space(3))) unsigned int*)l, 16, 0, 0);
}

// ---------------------------------------------------------------------------
// GEMM1: S = (H * K^T)/32 as bf16. 256x256 tile, BK=64, 512 threads (8 waves,
// 2Mx4N), 128KB LDS double-buffer. Counted-vmcnt pipeline, 2 tiles of
// loads in flight. Stage for tile kt+2 is issued into buf cur AFTER phase-3's
// post-MFMA barrier (all reads of buf cur provably complete); tile-top wait
// is vmcnt(8) (kt landed, kt+1 still flying), never 0 until kt=15.
// Grid 256 flat, 1 blk/CU, XCD-bijective 4x8 regions.
// ---------------------------------------------------------------------------
__global__ __launch_bounds__(512, 2) void gemm1_kernel(
    const u16* __restrict__ A, const u16* __restrict__ B,
    u16* __restrict__ S, int ldA, int ldB, int ldC)
{
  // As buf0 [0,16384), As buf1 [16384,32768), Bs buf0 [32768,49152), Bs buf1 [49152,65536)
  __shared__ __align__(16) u16 smem[65536];   // 128 KB

  const int tid  = threadIdx.x;
  const int lane = tid & 63;
  const int w    = tid >> 6;        // 0..7
  const int wr   = w >> 2;          // 0..1  (M)
  const int wc   = w & 3;           // 0..3  (N)
  const int quad = lane >> 4;
  const int cIn  = lane & 15;
  const int lrow   = lane >> 3;
  const int gchunk = (lane & 7) ^ lrow;

  const int flat = blockIdx.x;
  const int xcd  = flat & 7;
  const int i    = flat >> 3;                    // 0..31
  const int rowT = (xcd >> 1) * 4 + (i & 3);     // 0..15
  const int colT = (xcd & 1) * 8 + (i >> 2);     // 0..15
  const int rowBlk = rowT * 256;
  const int colBlk = colT * 256;

  f32x4 acc[8][4];
  #pragma unroll
  for (int a = 0; a < 8; ++a)
    #pragma unroll
    for (int b = 0; b < 4; ++b) acc[a][b] = {0.f, 0.f, 0.f, 0.f};

  // Stage one 256x64 operand tile: 4 x gload_lds(16B) per thread each.
  auto stageA = [&](int buf, int kt2) {
    #pragma unroll
    for (int l = 0; l < 4; ++l) {
      const u16* ga = A + (size_t)(rowBlk + l * 64 + w * 8 + lrow) * ldA
                        + kt2 * 64 + gchunk * 8;
      ld_lds16(ga, &smem[buf * 16384 + l * 4096 + w * 512]);
    }
  };
  auto stageB = [&](int buf, int kt2) {
    #pragma unroll
    for (int l = 0; l < 4; ++l) {
      const u16* gb = B + (size_t)(colBlk + l * 64 + w * 8 + lrow) * ldB
                        + kt2 * 64 + gchunk * 8;
      ld_lds16(gb, &smem[32768 + buf * 16384 + l * 4096 + w * 512]);
    }
  };

  stageA(0, 0);
  stageB(0, 0);
  stageA(1, 1);
  stageB(1, 1);                    // 16 loads/thread in flight

  for (int kt = 0; kt < 16; ++kt) {
    const int cur = kt & 1;
    const int aBase = cur * 16384;
    const int bBase = 32768 + cur * 16384;

    // Tile kt's 8 loads are the oldest; leave tile kt+1's 8 in flight.
    if (kt < 15) asm volatile("s_waitcnt vmcnt(8)" ::: "memory");
    else         asm volatile("s_waitcnt vmcnt(0)" ::: "memory");
    __builtin_amdgcn_s_barrier();          // all waves' portions landed
    __builtin_amdgcn_sched_barrier(0);

    bf16x8 bf[4][2];
    #pragma unroll
    for (int q = 0; q < 4; ++q) {
      if (q == 0) {
        #pragma unroll
        for (int ni = 0; ni < 4; ++ni)
          #pragma unroll
          for (int ks = 0; ks < 2; ++ks) {
            int row = wc * 64 + ni * 16 + cIn;
            int ch  = (ks * 4 + quad) ^ (row & 7);
            bf[ni][ks] = *(const bf16x8*)&smem[bBase + row * 64 + ch * 8];
          }
      }

      bf16x8 af[2][2];
      #pragma unroll
      for (int m = 0; m < 2; ++m)
        #pragma unroll
        for (int ks = 0; ks < 2; ++ks) {
          int row = wr * 128 + (q * 2 + m) * 16 + cIn;
          int ch  = (ks * 4 + quad) ^ (row & 7);
          af[m][ks] = *(const bf16x8*)&smem[aBase + row * 64 + ch * 8];
        }

      __builtin_amdgcn_s_barrier();
      asm volatile("s_waitcnt lgkmcnt(0)" ::: "memory");
      __builtin_amdgcn_sched_barrier(0);
      __builtin_amdgcn_s_setprio(1);
      #pragma unroll
      for (int m = 0; m < 2; ++m)
        #pragma unroll
        for (int ni = 0; ni < 4; ++ni)
          #pragma unroll
          for (int ks = 0; ks < 2; ++ks)
            acc[q * 2 + m][ni] = __builtin_amdgcn_mfma_f32_16x16x32_bf16(
                af[m][ks], bf[ni][ks], acc[q * 2 + m][ni], 0, 0, 0);
      __builtin_amdgcn_s_setprio(0);
      __builtin_amdgcn_sched_barrier(0);
      __builtin_amdgcn_s_barrier();        // post-MFMA: all reads of buf done
    }

    // Issue tile kt+2 into buf cur: safe, every wave passed the q=3 barrier
    // with lgkmcnt(0) drained => no outstanding reads of this buffer.
    if (kt + 2 < 16) {
      stageA(cur, kt + 2);
      stageB(cur, kt + 2);
    }
  }

  // Epilogue: 2 rounds through a 128x264-padded LDS buffer (conflict-light),
  // then coalesced 16B stores. Round R covers mi = 4R..4R+3.
  const float scale = 0.03125f;    // 1/sqrt(1024)
  u16* epi = smem;                 // 128 x 264 u16, aliases As (+ a bit of buf1)
  #pragma unroll
  for (int R = 0; R < 2; ++R) {
    #pragma unroll
    for (int m2 = 0; m2 < 4; ++m2) {
      int mi = R * 4 + m2;
      #pragma unroll
      for (int ni = 0; ni < 4; ++ni) {
        int col = wc * 64 + ni * 16 + cIn;
        #pragma unroll
        for (int r = 0; r < 4; ++r) {
          int er = wr * 64 + m2 * 16 + quad * 4 + r;   // 0..127
          epi[er * 264 + col] = f2bf(acc[mi][ni][r] * scale);
        }
      }
    }
    __syncthreads();
    #pragma unroll
    for (int it = 0; it < 8; ++it) {
      int idx = it * 512 + tid;            // 4096 chunks of 16B
      int er  = idx >> 5;                  // 0..127
      int c8  = idx & 31;                  // 0..31
      int grow = rowBlk + (er >> 6) * 128 + R * 64 + (er & 63);
      u32x4 v = *(const u32x4*)&epi[er * 264 + c8 * 8];
      *(u32x4*)&S[(size_t)grow * ldC + colBlk + c8 * 8] = v;
    }
    __syncthreads();
  }
}

// ---------------------------------------------------------------------------
// GEMM2: out = (P2 @ Vt^T) / L2. 128x128 tile, BK=64, 512 threads = 8 waves
// (2x2 spatial quadrants x 2-way split-K within the tile), TRIPLE-buffered
// LDS (96 KB) with counted vmcnt (4 in steady state, never 0 until the last
// tile), one raw s_barrier per K-tile. Odd-k waves reduce into even-k waves
// via LDS (stride-65 f32, conflict-free). Grid 256 flat (1 blk/CU).
// ---------------------------------------------------------------------------
__global__ __launch_bounds__(512, 2) void gemm2_kernel(
    const u16* __restrict__ A, const u16* __restrict__ B,
    float* __restrict__ Out, const float* __restrict__ L2,
    int ldA, int ldB, int ldC)
{
  // As: 3 bufs x 128x64 at 0; Bs: 3 bufs x 128x64 at 24576 (u16 units). 96 KB.
  __shared__ __align__(16) u16 smem[49152];

  const int tid  = threadIdx.x;
  const int lane = tid & 63;
  const int w    = tid >> 6;        // 0..7
  const int wk   = w & 1;           // k-slice within BK=64
  const int wrow = (w >> 1) & 1;    // M quadrant
  const int wcol = (w >> 2) & 1;    // N quadrant
  const int quad = lane >> 4;
  const int cIn  = lane & 15;
  const int lrow   = lane >> 3;
  const int gchunk = (lane & 7) ^ lrow;

  // 256 blocks = 32 rowT x 8 colT; each XCD owns 4 contiguous rowT.
  const int flat = blockIdx.x;
  const int xcd  = flat & 7;
  const int i    = flat >> 3;              // 0..31
  const int rowBlk = (xcd * 4 + (i & 3)) * 128;
  const int colBlk = (i >> 2) * 128;

  f32x4 acc[4][4];
  #pragma unroll
  for (int a = 0; a < 4; ++a)
    #pragma unroll
    for (int b = 0; b < 4; ++b) acc[a][b] = {0.f, 0.f, 0.f, 0.f};

  // Stage one K-tile (A 128x64 + B 128x64): 4 x gload_lds(16B) per thread.
  auto stage = [&](int buf, int kt) {
    int kk = kt * 64;
    #pragma unroll
    for (int t = 0; t < 2; ++t) {
      int rg = w * 2 + t;                  // 0..15
      const u16* ga = A + (size_t)(rowBlk + rg * 8 + lrow) * ldA + kk + gchunk * 8;
      ld_lds16(ga, &smem[buf * 8192 + rg * 512]);
      const u16* gb = B + (size_t)(colBlk + rg * 8 + lrow) * ldB + kk + gchunk * 8;
      ld_lds16(gb, &smem[24576 + buf * 8192 + rg * 512]);
    }
  };

  stage(0, 0);
  stage(1, 1);                             // 8 loads/thread in flight

  int cur = 0;
  for (int kt = 0; kt < 64; ++kt) {
    // Tile kt's 4 loads are the oldest; leave tile kt+1's 4 in flight.
    if (kt < 63) asm volatile("s_waitcnt vmcnt(4)" ::: "memory");
    else         asm volatile("s_waitcnt vmcnt(0)" ::: "memory");
    __builtin_amdgcn_s_barrier();          // all waves' portions landed
    __builtin_amdgcn_sched_barrier(0);

    if (kt + 2 < 64) {
      int nb = cur + 2; if (nb >= 3) nb -= 3;
      stage(nb, kt + 2);                   // buf freed by the barrier above
    }

    const int aBase = cur * 8192;
    const int bBase = 24576 + cur * 8192;
    bf16x8 af[4], bfr[4];
    #pragma unroll
    for (int mi = 0; mi < 4; ++mi) {
      int row = wrow * 64 + mi * 16 + cIn;
      int ch  = (wk * 4 + quad) ^ (row & 7);
      af[mi]  = *(const bf16x8*)&smem[aBase + row * 64 + ch * 8];
    }
    #pragma unroll
    for (int ni = 0; ni < 4; ++ni) {
      int row = wcol * 64 + ni * 16 + cIn;
      int ch  = (wk * 4 + quad) ^ (row & 7);
      bfr[ni] = *(const bf16x8*)&smem[bBase + row * 64 + ch * 8];
    }
    __builtin_amdgcn_s_setprio(1);
    #pragma unroll
    for (int mi = 0; mi < 4; ++mi)
      #pragma unroll
      for (int ni = 0; ni < 4; ++ni)
        acc[mi][ni] = __builtin_amdgcn_mfma_f32_16x16x32_bf16(
            af[mi], bfr[ni], acc[mi][ni], 0, 0, 0);
    __builtin_amdgcn_s_setprio(0);

    cur = (cur + 1 == 3) ? 0 : cur + 1;
  }

  // Cross-wave split-K reduction: odd-wk waves dump acc to LDS, even-wk waves
  // add, scale by 1/L2, store. Stride 65 f32 -> bank = (lane + j) % 32, free.
  float* red = (float*)smem;
  const int ow = w >> 1;                   // 0..3, same for wave pair (w, w^1)
  const int rbase = ow * 4160 + lane * 65;
  __syncthreads();
  if (wk == 1) {
    #pragma unroll
    for (int mi = 0; mi < 4; ++mi)
      #pragma unroll
      for (int ni = 0; ni < 4; ++ni)
        #pragma unroll
        for (int r = 0; r < 4; ++r)
          red[rbase + (mi * 4 + ni) * 4 + r] = acc[mi][ni][r];
  }
  __syncthreads();
  if (wk == 0) {
    #pragma unroll
    for (int mi = 0; mi < 4; ++mi) {
      #pragma unroll
      for (int r = 0; r < 4; ++r) {
        int row   = rowBlk + wrow * 64 + mi * 16 + quad * 4 + r;
        float inv = 1.0f / L2[row];
        #pragma unroll
        for (int ni = 0; ni < 4; ++ni) {
          int col = colBlk + wcol * 64 + ni * 16 + cIn;
          float v = acc[mi][ni][r] + red[rbase + (mi * 4 + ni) * 4 + r];
          __builtin_nontemporal_store(v * inv, &Out[(size_t)row * ldC + col]);
        }
      }
    }
  }
}

// Fused prep: [0,4096) cvt H, [4096,8192) cvt K, [8192,12288) transpose V.
__global__ __launch_bounds__(256) void prep_kernel(
    const float* __restrict__ H, const float* __restrict__ Kin,
    const float* __restrict__ V, u16* __restrict__ Hb, u16* __restrict__ Kb,
    u16* __restrict__ Vt)
{
  int b = blockIdx.x;
  if (b < 8192) {
    const float* src = (b < 4096) ? H : Kin;
    u16* dst = (b < 4096) ? Hb : Kb;
    int i = (b & 4095) * 256 + threadIdx.x;
    f32x4 v = __builtin_nontemporal_load(&((const f32x4*)src)[i]);
    ushort4 o;
    o.x = f2bf(v.x); o.y = f2bf(v.y); o.z = f2bf(v.z); o.w = f2bf(v.w);
    ((ushort4*)dst)[i] = o;
  } else {
    __shared__ float tile[32][33];
    b -= 8192;
    int c0 = (b & 31) * 32;
    int r0 = (b >> 5) * 32;
    int tx = threadIdx.x & 31, ty = threadIdx.x >> 5;
    #pragma unroll
    for (int s = 0; s < 32; s += 8)
      tile[ty + s][tx] = __builtin_nontemporal_load(
          &V[(size_t)(r0 + ty + s) * 1024 + c0 + tx]);
    __syncthreads();
    #pragma unroll
    for (int s = 0; s < 32; s += 8)
      Vt[(size_t)(c0 + ty + s) * 4096 + r0 + tx] = f2bf(tile[tx][ty + s]);
  }
}

// softmax2: computes L1 locally (row exp-sum), then p = exp(exp(s)/L1 * mask)
// in-place over S (bf16), row sum -> L2. One block per row, no atomics.
__global__ __launch_bounds__(256) void softmax2_kernel(
    u16* __restrict__ S, const float* __restrict__ mask,
    float* __restrict__ L2, int M)
{
  int row = blockIdx.x;
  u16* srow = S + (size_t)row * M;
  const float* mrow = mask + (size_t)row * M;
  const int base = threadIdx.x * 16;       // M == blockDim.x*16

  u16 sl[16];
  *(uint4*)(sl)     = *(const uint4*)(srow + base);
  *(uint4*)(sl + 8) = *(const uint4*)(srow + base + 8);

  float e[16];
  float s1 = 0.f;
  #pragma unroll
  for (int j = 0; j < 16; ++j) { e[j] = __expf(bf2f(sl[j])); s1 += e[j]; }

  __shared__ float wred[8];
  #pragma unroll
  for (int m = 1; m < 64; m <<= 1) s1 += __shfl_xor(s1, m, 64);
  if ((threadIdx.x & 63) == 0) wred[threadIdx.x >> 6] = s1;
  __syncthreads();
  float inv = 1.0f / (wred[0] + wred[1] + wred[2] + wred[3]);

  float mv[16];
  #pragma unroll
  for (int q = 0; q < 4; ++q) {
    f32x4 m4 = __builtin_nontemporal_load((const f32x4*)(mrow + base + q * 4));
    mv[q * 4 + 0] = m4.x; mv[q * 4 + 1] = m4.y;
    mv[q * 4 + 2] = m4.z; mv[q * 4 + 3] = m4.w;
  }

  float lsum = 0.f;
  #pragma unroll
  for (int j = 0; j < 16; ++j) {
    float p = __expf(e[j] * inv * mv[j]);
    lsum += p;
    sl[j] = f2bf(p);
  }
  *(uint4*)(srow + base)     = *(uint4*)(sl);
  *(uint4*)(srow + base + 8) = *(uint4*)(sl + 8);

  #pragma unroll
  for (int m = 1; m < 64; m <<= 1) lsum += __shfl_xor(lsum, m, 64);
  if ((threadIdx.x & 63) == 0) wred[4 + (threadIdx.x >> 6)] = lsum;
  __syncthreads();
  if (threadIdx.x == 0) L2[row] = wred[4] + wred[5] + wred[6] + wred[7];
}

extern "C" void kernel_launch(void* const* d_in, const int* in_sizes, int n_in,
                              void* d_out, int out_size, void* d_ws, size_t ws_size,
                              hipStream_t stream) {
  const float* H    = (const float*)d_in[0];
  const float* Kin  = (const float*)d_in[1];
  const float* V    = (const float*)d_in[2];
  const float* mask = (const float*)d_in[3];
  float* out = (float*)d_out;

  const int N = 4096, M = 4096, D = 1024;

  char* ws = (char*)d_ws;
  u16*   Hb = (u16*)(ws);
  u16*   Kb = (u16*)(ws + (8ull << 20));
  u16*   Vt = (u16*)(ws + (16ull << 20));
  u16*   S  = (u16*)(ws + (24ull << 20));
  float* L2 = (float*)(ws + (56ull << 20));

  prep_kernel<<<dim3(12288), dim3(256), 0, stream>>>(H, Kin, V, Hb, Kb, Vt);

  gemm1_kernel<<<dim3(256), dim3(512), 0, stream>>>(Hb, Kb, S, D, D, M);

  softmax2_kernel<<<dim3(N), dim3(256), 0, stream>>>(S, mask, L2, M);

  gemm2_kernel<<<dim3(256), dim3(512), 0, stream>>>(S, Vt, out, L2, M, M, D);
}

// Round 10
// 228.105 us; speedup vs baseline: 1.0066x; 1.0066x over previous
//
#include <hip/hip_runtime.h>
#include <cstdint>

typedef unsigned short u16;
typedef __bf16 bf16x8 __attribute__((ext_vector_type(8)));
typedef float f32x4 __attribute__((ext_vector_type(4)));
typedef unsigned int u32x4 __attribute__((ext_vector_type(4)));

__device__ __forceinline__ float bf2f(u16 h) {
  union { unsigned int u; float f; } v; v.u = ((unsigned int)h) << 16; return v.f;
}
__device__ __forceinline__ u16 f2bf(float f) {
  union { float f; unsigned int u; } v; v.f = f;
  unsigned int u = v.u;
  return (u16)((u + 0x7FFFu + ((u >> 16) & 1u)) >> 16);  // RNE, finite inputs
}

__device__ __forceinline__ void ld_lds16(const void* g, void* l) {
  __builtin_amdgcn_global_load_lds(
      (const __attribute__((address_space(1))) unsigned int*)g,
      (__attribute__((address_space(3))) unsigned int*)l, 16, 0, 0);
}

// ---------------------------------------------------------------------------
// GEMM1: S = (H * K^T)/32 as bf16. 256x256 tile, BK=64, 512 threads (8 waves,
// 2Mx4N), 128KB LDS double-buffer, counted-vmcnt pipeline (2 tiles of loads in
// flight, vmcnt(8) at tile top). NEW: 6 barriers/tile (dropped q0..q2
// post-MFMA barriers) + phase-ahead af ping-pong: quadrant q+1's ds_reads are
// issued before phase q's barrier, so the auto lgkm-wait at q+1 is ~1 phase
// old. bf reads hoisted to tile top. Grid 256 flat, 1 blk/CU.
// ---------------------------------------------------------------------------
__global__ __launch_bounds__(512, 2) void gemm1_kernel(
    const u16* __restrict__ A, const u16* __restrict__ B,
    u16* __restrict__ S, int ldA, int ldB, int ldC)
{
  // As buf0 [0,16384), As buf1 [16384,32768), Bs buf0 [32768,49152), Bs buf1 [49152,65536)
  __shared__ __align__(16) u16 smem[65536];   // 128 KB

  const int tid  = threadIdx.x;
  const int lane = tid & 63;
  const int w    = tid >> 6;        // 0..7
  const int wr   = w >> 2;          // 0..1  (M)
  const int wc   = w & 3;           // 0..3  (N)
  const int quad = lane >> 4;
  const int cIn  = lane & 15;
  const int lrow   = lane >> 3;
  const int gchunk = (lane & 7) ^ lrow;

  const int flat = blockIdx.x;
  const int xcd  = flat & 7;
  const int i    = flat >> 3;                    // 0..31
  const int rowT = (xcd >> 1) * 4 + (i & 3);     // 0..15
  const int colT = (xcd & 1) * 8 + (i >> 2);     // 0..15
  const int rowBlk = rowT * 256;
  const int colBlk = colT * 256;

  f32x4 acc[8][4];
  #pragma unroll
  for (int a = 0; a < 8; ++a)
    #pragma unroll
    for (int b = 0; b < 4; ++b) acc[a][b] = {0.f, 0.f, 0.f, 0.f};

  // Stage one 256x64 operand tile: 4 x gload_lds(16B) per thread each.
  auto stageA = [&](int buf, int kt2) {
    #pragma unroll
    for (int l = 0; l < 4; ++l) {
      const u16* ga = A + (size_t)(rowBlk + l * 64 + w * 8 + lrow) * ldA
                        + kt2 * 64 + gchunk * 8;
      ld_lds16(ga, &smem[buf * 16384 + l * 4096 + w * 512]);
    }
  };
  auto stageB = [&](int buf, int kt2) {
    #pragma unroll
    for (int l = 0; l < 4; ++l) {
      const u16* gb = B + (size_t)(colBlk + l * 64 + w * 8 + lrow) * ldB
                        + kt2 * 64 + gchunk * 8;
      ld_lds16(gb, &smem[32768 + buf * 16384 + l * 4096 + w * 512]);
    }
  };

  stageA(0, 0);
  stageB(0, 0);
  stageA(1, 1);
  stageB(1, 1);                    // 16 loads/thread in flight

  for (int kt = 0; kt < 16; ++kt) {
    const int cur = kt & 1;
    const int aBase = cur * 16384;
    const int bBase = 32768 + cur * 16384;

    // Tile kt's 8 loads are the oldest; leave tile kt+1's 8 in flight.
    if (kt < 15) asm volatile("s_waitcnt vmcnt(8)" ::: "memory");
    else         asm volatile("s_waitcnt vmcnt(0)" ::: "memory");
    __builtin_amdgcn_s_barrier();          // all waves' portions landed
    __builtin_amdgcn_sched_barrier(0);

    // Tile-top reads: all B fragments + quadrant-0 A fragments (12 reads).
    bf16x8 bf[4][2];
    #pragma unroll
    for (int ni = 0; ni < 4; ++ni)
      #pragma unroll
      for (int ks = 0; ks < 2; ++ks) {
        int row = wc * 64 + ni * 16 + cIn;
        int ch  = (ks * 4 + quad) ^ (row & 7);
        bf[ni][ks] = *(const bf16x8*)&smem[bBase + row * 64 + ch * 8];
      }
    bf16x8 afA[2][2], afB[2][2];
    #pragma unroll
    for (int m = 0; m < 2; ++m)
      #pragma unroll
      for (int ks = 0; ks < 2; ++ks) {
        int row = wr * 128 + m * 16 + cIn;
        int ch  = (ks * 4 + quad) ^ (row & 7);
        afA[m][ks] = *(const bf16x8*)&smem[aBase + row * 64 + ch * 8];
      }

    #pragma unroll
    for (int q = 0; q < 4; ++q) {
      // Issue next quadrant's A-fragment reads into the other af buffer.
      if (q < 3) {
        #pragma unroll
        for (int m = 0; m < 2; ++m)
          #pragma unroll
          for (int ks = 0; ks < 2; ++ks) {
            int row = wr * 128 + ((q + 1) * 2 + m) * 16 + cIn;
            int ch  = (ks * 4 + quad) ^ (row & 7);
            bf16x8 v = *(const bf16x8*)&smem[aBase + row * 64 + ch * 8];
            if (q & 1) afA[m][ks] = v; else afB[m][ks] = v;
          }
      }
      __builtin_amdgcn_sched_barrier(0);
      __builtin_amdgcn_s_barrier();        // phase lockstep
      __builtin_amdgcn_sched_barrier(0);
      __builtin_amdgcn_s_setprio(1);
      // Compiler auto-inserts the counted lgkm wait for this phase's frags,
      // leaving the just-issued next-phase reads outstanding.
      #pragma unroll
      for (int m = 0; m < 2; ++m)
        #pragma unroll
        for (int ni = 0; ni < 4; ++ni)
          #pragma unroll
          for (int ks = 0; ks < 2; ++ks) {
            if (q & 1)
              acc[q * 2 + m][ni] = __builtin_amdgcn_mfma_f32_16x16x32_bf16(
                  afB[m][ks], bf[ni][ks], acc[q * 2 + m][ni], 0, 0, 0);
            else
              acc[q * 2 + m][ni] = __builtin_amdgcn_mfma_f32_16x16x32_bf16(
                  afA[m][ks], bf[ni][ks], acc[q * 2 + m][ni], 0, 0, 0);
          }
      __builtin_amdgcn_s_setprio(0);
      __builtin_amdgcn_sched_barrier(0);
    }
    __builtin_amdgcn_s_barrier();          // all reads of buf cur serviced

    // Issue tile kt+2 into buf cur: safe, all waves drained their LDS reads.
    if (kt + 2 < 16) {
      stageA(cur, kt + 2);
      stageB(cur, kt + 2);
    }
  }

  // Epilogue: 2 rounds through a 128x264-padded LDS buffer (conflict-light),
  // then coalesced 16B stores. Round R covers mi = 4R..4R+3.
  const float scale = 0.03125f;    // 1/sqrt(1024)
  u16* epi = smem;                 // 128 x 264 u16, aliases As (+ a bit of buf1)
  #pragma unroll
  for (int R = 0; R < 2; ++R) {
    #pragma unroll
    for (int m2 = 0; m2 < 4; ++m2) {
      int mi = R * 4 + m2;
      #pragma unroll
      for (int ni = 0; ni < 4; ++ni) {
        int col = wc * 64 + ni * 16 + cIn;
        #pragma unroll
        for (int r = 0; r < 4; ++r) {
          int er = wr * 64 + m2 * 16 + quad * 4 + r;   // 0..127
          epi[er * 264 + col] = f2bf(acc[mi][ni][r] * scale);
        }
      }
    }
    __syncthreads();
    #pragma unroll
    for (int it = 0; it < 8; ++it) {
      int idx = it * 512 + tid;            // 4096 chunks of 16B
      int er  = idx >> 5;                  // 0..127
      int c8  = idx & 31;                  // 0..31
      int grow = rowBlk + (er >> 6) * 128 + R * 64 + (er & 63);
      u32x4 v = *(const u32x4*)&epi[er * 264 + c8 * 8];
      *(u32x4*)&S[(size_t)grow * ldC + colBlk + c8 * 8] = v;
    }
    __syncthreads();
  }
}

// ---------------------------------------------------------------------------
// GEMM2: out = (P2 @ Vt^T) / L2. 128x128 tile, BK=64, 512 threads = 8 waves
// (2x2 spatial quadrants x 2-way split-K within the tile), TRIPLE-buffered
// LDS (96 KB) with counted vmcnt (4 in steady state, never 0 until the last
// tile), one raw s_barrier per K-tile. Odd-k waves reduce into even-k waves
// via LDS (stride-65 f32, conflict-free). Grid 256 flat (1 blk/CU).
// (unchanged this round)
// ---------------------------------------------------------------------------
__global__ __launch_bounds__(512, 2) void gemm2_kernel(
    const u16* __restrict__ A, const u16* __restrict__ B,
    float* __restrict__ Out, const float* __restrict__ L2,
    int ldA, int ldB, int ldC)
{
  // As: 3 bufs x 128x64 at 0; Bs: 3 bufs x 128x64 at 24576 (u16 units). 96 KB.
  __shared__ __align__(16) u16 smem[49152];

  const int tid  = threadIdx.x;
  const int lane = tid & 63;
  const int w    = tid >> 6;        // 0..7
  const int wk   = w & 1;           // k-slice within BK=64
  const int wrow = (w >> 1) & 1;    // M quadrant
  const int wcol = (w >> 2) & 1;    // N quadrant
  const int quad = lane >> 4;
  const int cIn  = lane & 15;
  const int lrow   = lane >> 3;
  const int gchunk = (lane & 7) ^ lrow;

  // 256 blocks = 32 rowT x 8 colT; each XCD owns 4 contiguous rowT.
  const int flat = blockIdx.x;
  const int xcd  = flat & 7;
  const int i    = flat >> 3;              // 0..31
  const int rowBlk = (xcd * 4 + (i & 3)) * 128;
  const int colBlk = (i >> 2) * 128;

  f32x4 acc[4][4];
  #pragma unroll
  for (int a = 0; a < 4; ++a)
    #pragma unroll
    for (int b = 0; b < 4; ++b) acc[a][b] = {0.f, 0.f, 0.f, 0.f};

  // Stage one K-tile (A 128x64 + B 128x64): 4 x gload_lds(16B) per thread.
  auto stage = [&](int buf, int kt) {
    int kk = kt * 64;
    #pragma unroll
    for (int t = 0; t < 2; ++t) {
      int rg = w * 2 + t;                  // 0..15
      const u16* ga = A + (size_t)(rowBlk + rg * 8 + lrow) * ldA + kk + gchunk * 8;
      ld_lds16(ga, &smem[buf * 8192 + rg * 512]);
      const u16* gb = B + (size_t)(colBlk + rg * 8 + lrow) * ldB + kk + gchunk * 8;
      ld_lds16(gb, &smem[24576 + buf * 8192 + rg * 512]);
    }
  };

  stage(0, 0);
  stage(1, 1);                             // 8 loads/thread in flight

  int cur = 0;
  for (int kt = 0; kt < 64; ++kt) {
    // Tile kt's 4 loads are the oldest; leave tile kt+1's 4 in flight.
    if (kt < 63) asm volatile("s_waitcnt vmcnt(4)" ::: "memory");
    else         asm volatile("s_waitcnt vmcnt(0)" ::: "memory");
    __builtin_amdgcn_s_barrier();          // all waves' portions landed
    __builtin_amdgcn_sched_barrier(0);

    if (kt + 2 < 64) {
      int nb = cur + 2; if (nb >= 3) nb -= 3;
      stage(nb, kt + 2);                   // buf freed by the barrier above
    }

    const int aBase = cur * 8192;
    const int bBase = 24576 + cur * 8192;
    bf16x8 af[4], bfr[4];
    #pragma unroll
    for (int mi = 0; mi < 4; ++mi) {
      int row = wrow * 64 + mi * 16 + cIn;
      int ch  = (wk * 4 + quad) ^ (row & 7);
      af[mi]  = *(const bf16x8*)&smem[aBase + row * 64 + ch * 8];
    }
    #pragma unroll
    for (int ni = 0; ni < 4; ++ni) {
      int row = wcol * 64 + ni * 16 + cIn;
      int ch  = (wk * 4 + quad) ^ (row & 7);
      bfr[ni] = *(const bf16x8*)&smem[bBase + row * 64 + ch * 8];
    }
    __builtin_amdgcn_s_setprio(1);
    #pragma unroll
    for (int mi = 0; mi < 4; ++mi)
      #pragma unroll
      for (int ni = 0; ni < 4; ++ni)
        acc[mi][ni] = __builtin_amdgcn_mfma_f32_16x16x32_bf16(
            af[mi], bfr[ni], acc[mi][ni], 0, 0, 0);
    __builtin_amdgcn_s_setprio(0);

    cur = (cur + 1 == 3) ? 0 : cur + 1;
  }

  // Cross-wave split-K reduction: odd-wk waves dump acc to LDS, even-wk waves
  // add, scale by 1/L2, store. Stride 65 f32 -> bank = (lane + j) % 32, free.
  float* red = (float*)smem;
  const int ow = w >> 1;                   // 0..3, same for wave pair (w, w^1)
  const int rbase = ow * 4160 + lane * 65;
  __syncthreads();
  if (wk == 1) {
    #pragma unroll
    for (int mi = 0; mi < 4; ++mi)
      #pragma unroll
      for (int ni = 0; ni < 4; ++ni)
        #pragma unroll
        for (int r = 0; r < 4; ++r)
          red[rbase + (mi * 4 + ni) * 4 + r] = acc[mi][ni][r];
  }
  __syncthreads();
  if (wk == 0) {
    #pragma unroll
    for (int mi = 0; mi < 4; ++mi) {
      #pragma unroll
      for (int r = 0; r < 4; ++r) {
        int row   = rowBlk + wrow * 64 + mi * 16 + quad * 4 + r;
        float inv = 1.0f / L2[row];
        #pragma unroll
        for (int ni = 0; ni < 4; ++ni) {
          int col = colBlk + wcol * 64 + ni * 16 + cIn;
          float v = acc[mi][ni][r] + red[rbase + (mi * 4 + ni) * 4 + r];
          __builtin_nontemporal_store(v * inv, &Out[(size_t)row * ldC + col]);
        }
      }
    }
  }
}

// Fused prep: [0,4096) cvt H, [4096,8192) cvt K, [8192,12288) transpose V.
// NEW: transpose writes Vt in 16B chunks (128 threads x u32x4) instead of
// per-element 2B stores.
__global__ __launch_bounds__(256) void prep_kernel(
    const float* __restrict__ H, const float* __restrict__ Kin,
    const float* __restrict__ V, u16* __restrict__ Hb, u16* __restrict__ Kb,
    u16* __restrict__ Vt)
{
  int b = blockIdx.x;
  if (b < 8192) {
    const float* src = (b < 4096) ? H : Kin;
    u16* dst = (b < 4096) ? Hb : Kb;
    int i = (b & 4095) * 256 + threadIdx.x;
    f32x4 v = __builtin_nontemporal_load(&((const f32x4*)src)[i]);
    ushort4 o;
    o.x = f2bf(v.x); o.y = f2bf(v.y); o.z = f2bf(v.z); o.w = f2bf(v.w);
    ((ushort4*)dst)[i] = o;
  } else {
    __shared__ float tile[32][33];
    b -= 8192;
    int c0 = (b & 31) * 32;
    int r0 = (b >> 5) * 32;
    int tx = threadIdx.x & 31, ty = threadIdx.x >> 5;
    #pragma unroll
    for (int s = 0; s < 32; s += 8)
      tile[ty + s][tx] = __builtin_nontemporal_load(
          &V[(size_t)(r0 + ty + s) * 1024 + c0 + tx]);
    __syncthreads();
    if (threadIdx.x < 128) {
      int vr = threadIdx.x >> 2;           // 0..31 -> Vt row c0+vr
      int ch = threadIdx.x & 3;            // 16B chunk: r-offset ch*8
      u32x4 ov;
      #pragma unroll
      for (int p = 0; p < 4; ++p) {
        unsigned int lo = f2bf(tile[ch * 8 + p * 2][vr]);
        unsigned int hi = f2bf(tile[ch * 8 + p * 2 + 1][vr]);
        ov[p] = lo | (hi << 16);
      }
      *(u32x4*)&Vt[(size_t)(c0 + vr) * 4096 + r0 + ch * 8] = ov;
    }
  }
}

// softmax2: computes L1 locally (row exp-sum), then p = exp(exp(s)/L1 * mask)
// in-place over S (bf16), row sum -> L2. One block per row, no atomics.
__global__ __launch_bounds__(256) void softmax2_kernel(
    u16* __restrict__ S, const float* __restrict__ mask,
    float* __restrict__ L2, int M)
{
  int row = blockIdx.x;
  u16* srow = S + (size_t)row * M;
  const float* mrow = mask + (size_t)row * M;
  const int base = threadIdx.x * 16;       // M == blockDim.x*16

  u16 sl[16];
  *(uint4*)(sl)     = *(const uint4*)(srow + base);
  *(uint4*)(sl + 8) = *(const uint4*)(srow + base + 8);

  float e[16];
  float s1 = 0.f;
  #pragma unroll
  for (int j = 0; j < 16; ++j) { e[j] = __expf(bf2f(sl[j])); s1 += e[j]; }

  __shared__ float wred[8];
  #pragma unroll
  for (int m = 1; m < 64; m <<= 1) s1 += __shfl_xor(s1, m, 64);
  if ((threadIdx.x & 63) == 0) wred[threadIdx.x >> 6] = s1;
  __syncthreads();
  float inv = 1.0f / (wred[0] + wred[1] + wred[2] + wred[3]);

  float mv[16];
  #pragma unroll
  for (int q = 0; q < 4; ++q) {
    f32x4 m4 = __builtin_nontemporal_load((const f32x4*)(mrow + base + q * 4));
    mv[q * 4 + 0] = m4.x; mv[q * 4 + 1] = m4.y;
    mv[q * 4 + 2] = m4.z; mv[q * 4 + 3] = m4.w;
  }

  float lsum = 0.f;
  #pragma unroll
  for (int j = 0; j < 16; ++j) {
    float p = __expf(e[j] * inv * mv[j]);
    lsum += p;
    sl[j] = f2bf(p);
  }
  *(uint4*)(srow + base)     = *(uint4*)(sl);
  *(uint4*)(srow + base + 8) = *(uint4*)(sl + 8);

  #pragma unroll
  for (int m = 1; m < 64; m <<= 1) lsum += __shfl_xor(lsum, m, 64);
  if ((threadIdx.x & 63) == 0) wred[4 + (threadIdx.x >> 6)] = lsum;
  __syncthreads();
  if (threadIdx.x == 0) L2[row] = wred[4] + wred[5] + wred[6] + wred[7];
}

extern "C" void kernel_launch(void* const* d_in, const int* in_sizes, int n_in,
                              void* d_out, int out_size, void* d_ws, size_t ws_size,
                              hipStream_t stream) {
  const float* H    = (const float*)d_in[0];
  const float* Kin  = (const float*)d_in[1];
  const float* V    = (const float*)d_in[2];
  const float* mask = (const float*)d_in[3];
  float* out = (float*)d_out;

  const int N = 4096, M = 4096, D = 1024;

  char* ws = (char*)d_ws;
  u16*   Hb = (u16*)(ws);
  u16*   Kb = (u16*)(ws + (8ull << 20));
  u16*   Vt = (u16*)(ws + (16ull << 20));
  u16*   S  = (u16*)(ws + (24ull << 20));
  float* L2 = (float*)(ws + (56ull << 20));

  prep_kernel<<<dim3(12288), dim3(256), 0, stream>>>(H, Kin, V, Hb, Kb, Vt);

  gemm1_kernel<<<dim3(256), dim3(512), 0, stream>>>(Hb, Kb, S, D, D, M);

  softmax2_kernel<<<dim3(N), dim3(256), 0, stream>>>(S, mask, L2, M);

  gemm2_kernel<<<dim3(256), dim3(512), 0, stream>>>(S, Vt, out, L2, M, M, D);
}

// Round 14
// 227.368 us; speedup vs baseline: 1.0099x; 1.0032x over previous
//
#include <hip/hip_runtime.h>
#include <cstdint>

typedef unsigned short u16;
typedef __bf16 bf16x8 __attribute__((ext_vector_type(8)));
typedef float f32x4 __attribute__((ext_vector_type(4)));
typedef unsigned int u32x4 __attribute__((ext_vector_type(4)));

__device__ __forceinline__ float bf2f(u16 h) {
  union { unsigned int u; float f; } v; v.u = ((unsigned int)h) << 16; return v.f;
}
__device__ __forceinline__ u16 f2bf(float f) {
  union { float f; unsigned int u; } v; v.f = f;
  unsigned int u = v.u;
  return (u16)((u + 0x7FFFu + ((u >> 16) & 1u)) >> 16);  // RNE, finite inputs
}

__device__ __forceinline__ void ld_lds16(const void* g, void* l) {
  __builtin_amdgcn_global_load_lds(
      (const __attribute__((address_space(1))) unsigned int*)g,
      (__attribute__((address_space(3))) unsigned int*)l, 16, 0, 0);
}

// ---------------------------------------------------------------------------
// GEMM1: S = (H * K^T)/32 as bf16. 256x256 tile, BK=64, 512 threads (8 waves,
// 2Mx4N), 128KB LDS double-buffer, counted-vmcnt pipeline (2 tiles of loads in
// flight, vmcnt(8) at tile top). Phase-ahead af ping-pong with EXPLICIT
// counted lgkm waits: phases 0-2 wait lgkmcnt(4) (leaving the 4 pre-issued
// next-quadrant reads in flight), phase 3 waits lgkmcnt(0). 5 barriers/tile
// (top, q1..q3 lockstep, final). Grid 256 flat, 1 blk/CU.
// ---------------------------------------------------------------------------
__global__ __launch_bounds__(512, 2) void gemm1_kernel(
    const u16* __restrict__ A, const u16* __restrict__ B,
    u16* __restrict__ S, int ldA, int ldB, int ldC)
{
  // As buf0 [0,16384), As buf1 [16384,32768), Bs buf0 [32768,49152), Bs buf1 [49152,65536)
  __shared__ __align__(16) u16 smem[65536];   // 128 KB

  const int tid  = threadIdx.x;
  const int lane = tid & 63;
  const int w    = tid >> 6;        // 0..7
  const int wr   = w >> 2;          // 0..1  (M)
  const int wc   = w & 3;           // 0..3  (N)
  const int quad = lane >> 4;
  const int cIn  = lane & 15;
  const int lrow   = lane >> 3;
  const int gchunk = (lane & 7) ^ lrow;

  const int flat = blockIdx.x;
  const int xcd  = flat & 7;
  const int i    = flat >> 3;                    // 0..31
  const int rowT = (xcd >> 1) * 4 + (i & 3);     // 0..15
  const int colT = (xcd & 1) * 8 + (i >> 2);     // 0..15
  const int rowBlk = rowT * 256;
  const int colBlk = colT * 256;

  f32x4 acc[8][4];
  #pragma unroll
  for (int a = 0; a < 8; ++a)
    #pragma unroll
    for (int b = 0; b < 4; ++b) acc[a][b] = {0.f, 0.f, 0.f, 0.f};

  // Stage one 256x64 operand tile: 4 x gload_lds(16B) per thread each.
  auto stageA = [&](int buf, int kt2) {
    #pragma unroll
    for (int l = 0; l < 4; ++l) {
      const u16* ga = A + (size_t)(rowBlk + l * 64 + w * 8 + lrow) * ldA
                        + kt2 * 64 + gchunk * 8;
      ld_lds16(ga, &smem[buf * 16384 + l * 4096 + w * 512]);
    }
  };
  auto stageB = [&](int buf, int kt2) {
    #pragma unroll
    for (int l = 0; l < 4; ++l) {
      const u16* gb = B + (size_t)(colBlk + l * 64 + w * 8 + lrow) * ldB
                        + kt2 * 64 + gchunk * 8;
      ld_lds16(gb, &smem[32768 + buf * 16384 + l * 4096 + w * 512]);
    }
  };

  stageA(0, 0);
  stageB(0, 0);
  stageA(1, 1);
  stageB(1, 1);                    // 16 loads/thread in flight

  for (int kt = 0; kt < 16; ++kt) {
    const int cur = kt & 1;
    const int aBase = cur * 16384;
    const int bBase = 32768 + cur * 16384;

    // Tile kt's 8 loads are the oldest; leave tile kt+1's 8 in flight.
    if (kt < 15) asm volatile("s_waitcnt vmcnt(8)" ::: "memory");
    else         asm volatile("s_waitcnt vmcnt(0)" ::: "memory");
    __builtin_amdgcn_s_barrier();          // all waves' portions landed
    __builtin_amdgcn_sched_barrier(0);

    // Tile-top reads: all B fragments + quadrant-0 A fragments (12 reads).
    bf16x8 bf[4][2];
    #pragma unroll
    for (int ni = 0; ni < 4; ++ni)
      #pragma unroll
      for (int ks = 0; ks < 2; ++ks) {
        int row = wc * 64 + ni * 16 + cIn;
        int ch  = (ks * 4 + quad) ^ (row & 7);
        bf[ni][ks] = *(const bf16x8*)&smem[bBase + row * 64 + ch * 8];
      }
    bf16x8 afA[2][2], afB[2][2];
    #pragma unroll
    for (int m = 0; m < 2; ++m)
      #pragma unroll
      for (int ks = 0; ks < 2; ++ks) {
        int row = wr * 128 + m * 16 + cIn;
        int ch  = (ks * 4 + quad) ^ (row & 7);
        afA[m][ks] = *(const bf16x8*)&smem[aBase + row * 64 + ch * 8];
      }

    #pragma unroll
    for (int q = 0; q < 4; ++q) {
      // Issue next quadrant's A-fragment reads into the other af buffer.
      if (q < 3) {
        #pragma unroll
        for (int m = 0; m < 2; ++m)
          #pragma unroll
          for (int ks = 0; ks < 2; ++ks) {
            int row = wr * 128 + ((q + 1) * 2 + m) * 16 + cIn;
            int ch  = (ks * 4 + quad) ^ (row & 7);
            bf16x8 v = *(const bf16x8*)&smem[aBase + row * 64 + ch * 8];
            if (q & 1) afA[m][ks] = v; else afB[m][ks] = v;
          }
      }
      __builtin_amdgcn_sched_barrier(0);
      if (q > 0) __builtin_amdgcn_s_barrier();   // phase lockstep (q0: top barrier)
      // Explicit counted LDS wait: this phase's frags are older than the 4
      // just-issued next-phase reads -> lgkmcnt(4) drains exactly what's
      // needed, keeping the prefetch in flight. Phase 3 has no prefetch.
      if (q < 3) asm volatile("s_waitcnt lgkmcnt(4)" ::: "memory");
      else       asm volatile("s_waitcnt lgkmcnt(0)" ::: "memory");
      __builtin_amdgcn_sched_barrier(0);
      __builtin_amdgcn_s_setprio(1);
      #pragma unroll
      for (int m = 0; m < 2; ++m)
        #pragma unroll
        for (int ni = 0; ni < 4; ++ni)
          #pragma unroll
          for (int ks = 0; ks < 2; ++ks) {
            if (q & 1)
              acc[q * 2 + m][ni] = __builtin_amdgcn_mfma_f32_16x16x32_bf16(
                  afB[m][ks], bf[ni][ks], acc[q * 2 + m][ni], 0, 0, 0);
            else
              acc[q * 2 + m][ni] = __builtin_amdgcn_mfma_f32_16x16x32_bf16(
                  afA[m][ks], bf[ni][ks], acc[q * 2 + m][ni], 0, 0, 0);
          }
      __builtin_amdgcn_s_setprio(0);
      __builtin_amdgcn_sched_barrier(0);
    }
    __builtin_amdgcn_s_barrier();          // all reads of buf cur drained

    // Issue tile kt+2 into buf cur: safe, every wave drained lgkm before the
    // final barrier (phase 3 waits lgkmcnt(0) before its MFMA).
    if (kt + 2 < 16) {
      stageA(cur, kt + 2);
      stageB(cur, kt + 2);
    }
  }

  // Epilogue: 2 rounds through a 128x264-padded LDS buffer (conflict-light),
  // then coalesced 16B stores. Round R covers mi = 4R..4R+3.
  const float scale = 0.03125f;    // 1/sqrt(1024)
  u16* epi = smem;                 // 128 x 264 u16, aliases As (+ a bit of buf1)
  #pragma unroll
  for (int R = 0; R < 2; ++R) {
    #pragma unroll
    for (int m2 = 0; m2 < 4; ++m2) {
      int mi = R * 4 + m2;
      #pragma unroll
      for (int ni = 0; ni < 4; ++ni) {
        int col = wc * 64 + ni * 16 + cIn;
        #pragma unroll
        for (int r = 0; r < 4; ++r) {
          int er = wr * 64 + m2 * 16 + quad * 4 + r;   // 0..127
          epi[er * 264 + col] = f2bf(acc[mi][ni][r] * scale);
        }
      }
    }
    __syncthreads();
    #pragma unroll
    for (int it = 0; it < 8; ++it) {
      int idx = it * 512 + tid;            // 4096 chunks of 16B
      int er  = idx >> 5;                  // 0..127
      int c8  = idx & 31;                  // 0..31
      int grow = rowBlk + (er >> 6) * 128 + R * 64 + (er & 63);
      u32x4 v = *(const u32x4*)&epi[er * 264 + c8 * 8];
      *(u32x4*)&S[(size_t)grow * ldC + colBlk + c8 * 8] = v;
    }
    __syncthreads();
  }
}

// ---------------------------------------------------------------------------
// GEMM2: out = (P2 @ Vt^T) / L2. 128x128 tile, BK=64, 512 threads = 8 waves
// (2x2 spatial quadrants x 2-way split-K within the tile), TRIPLE-buffered
// LDS (96 KB) with counted vmcnt (4 in steady state, never 0 until the last
// tile), one raw s_barrier per K-tile. Odd-k waves reduce into even-k waves
// via LDS (stride-65 f32, conflict-free). Grid 256 flat (1 blk/CU).
// ---------------------------------------------------------------------------
__global__ __launch_bounds__(512, 2) void gemm2_kernel(
    const u16* __restrict__ A, const u16* __restrict__ B,
    float* __restrict__ Out, const float* __restrict__ L2,
    int ldA, int ldB, int ldC)
{
  // As: 3 bufs x 128x64 at 0; Bs: 3 bufs x 128x64 at 24576 (u16 units). 96 KB.
  __shared__ __align__(16) u16 smem[49152];

  const int tid  = threadIdx.x;
  const int lane = tid & 63;
  const int w    = tid >> 6;        // 0..7
  const int wk   = w & 1;           // k-slice within BK=64
  const int wrow = (w >> 1) & 1;    // M quadrant
  const int wcol = (w >> 2) & 1;    // N quadrant
  const int quad = lane >> 4;
  const int cIn  = lane & 15;
  const int lrow   = lane >> 3;
  const int gchunk = (lane & 7) ^ lrow;

  // 256 blocks = 32 rowT x 8 colT; each XCD owns 4 contiguous rowT.
  const int flat = blockIdx.x;
  const int xcd  = flat & 7;
  const int i    = flat >> 3;              // 0..31
  const int rowBlk = (xcd * 4 + (i & 3)) * 128;
  const int colBlk = (i >> 2) * 128;

  f32x4 acc[4][4];
  #pragma unroll
  for (int a = 0; a < 4; ++a)
    #pragma unroll
    for (int b = 0; b < 4; ++b) acc[a][b] = {0.f, 0.f, 0.f, 0.f};

  // Stage one K-tile (A 128x64 + B 128x64): 4 x gload_lds(16B) per thread.
  auto stage = [&](int buf, int kt) {
    int kk = kt * 64;
    #pragma unroll
    for (int t = 0; t < 2; ++t) {
      int rg = w * 2 + t;                  // 0..15
      const u16* ga = A + (size_t)(rowBlk + rg * 8 + lrow) * ldA + kk + gchunk * 8;
      ld_lds16(ga, &smem[buf * 8192 + rg * 512]);
      const u16* gb = B + (size_t)(colBlk + rg * 8 + lrow) * ldB + kk + gchunk * 8;
      ld_lds16(gb, &smem[24576 + buf * 8192 + rg * 512]);
    }
  };

  stage(0, 0);
  stage(1, 1);                             // 8 loads/thread in flight

  int cur = 0;
  for (int kt = 0; kt < 64; ++kt) {
    // Tile kt's 4 loads are the oldest; leave tile kt+1's 4 in flight.
    if (kt < 63) asm volatile("s_waitcnt vmcnt(4)" ::: "memory");
    else         asm volatile("s_waitcnt vmcnt(0)" ::: "memory");
    __builtin_amdgcn_s_barrier();          // all waves' portions landed
    __builtin_amdgcn_sched_barrier(0);

    if (kt + 2 < 64) {
      int nb = cur + 2; if (nb >= 3) nb -= 3;
      stage(nb, kt + 2);                   // buf freed by the barrier above
    }

    const int aBase = cur * 8192;
    const int bBase = 24576 + cur * 8192;
    bf16x8 af[4], bfr[4];
    #pragma unroll
    for (int mi = 0; mi < 4; ++mi) {
      int row = wrow * 64 + mi * 16 + cIn;
      int ch  = (wk * 4 + quad) ^ (row & 7);
      af[mi]  = *(const bf16x8*)&smem[aBase + row * 64 + ch * 8];
    }
    #pragma unroll
    for (int ni = 0; ni < 4; ++ni) {
      int row = wcol * 64 + ni * 16 + cIn;
      int ch  = (wk * 4 + quad) ^ (row & 7);
      bfr[ni] = *(const bf16x8*)&smem[bBase + row * 64 + ch * 8];
    }
    __builtin_amdgcn_s_setprio(1);
    #pragma unroll
    for (int mi = 0; mi < 4; ++mi)
      #pragma unroll
      for (int ni = 0; ni < 4; ++ni)
        acc[mi][ni] = __builtin_amdgcn_mfma_f32_16x16x32_bf16(
            af[mi], bfr[ni], acc[mi][ni], 0, 0, 0);
    __builtin_amdgcn_s_setprio(0);

    cur = (cur + 1 == 3) ? 0 : cur + 1;
  }

  // Cross-wave split-K reduction: odd-wk waves dump acc to LDS, even-wk waves
  // add, scale by 1/L2, store. Stride 65 f32 -> bank = (lane + j) % 32, free.
  float* red = (float*)smem;
  const int ow = w >> 1;                   // 0..3, same for wave pair (w, w^1)
  const int rbase = ow * 4160 + lane * 65;
  __syncthreads();
  if (wk == 1) {
    #pragma unroll
    for (int mi = 0; mi < 4; ++mi)
      #pragma unroll
      for (int ni = 0; ni < 4; ++ni)
        #pragma unroll
        for (int r = 0; r < 4; ++r)
          red[rbase + (mi * 4 + ni) * 4 + r] = acc[mi][ni][r];
  }
  __syncthreads();
  if (wk == 0) {
    #pragma unroll
    for (int mi = 0; mi < 4; ++mi) {
      #pragma unroll
      for (int r = 0; r < 4; ++r) {
        int row   = rowBlk + wrow * 64 + mi * 16 + quad * 4 + r;
        float inv = 1.0f / L2[row];
        #pragma unroll
        for (int ni = 0; ni < 4; ++ni) {
          int col = colBlk + wcol * 64 + ni * 16 + cIn;
          float v = acc[mi][ni][r] + red[rbase + (mi * 4 + ni) * 4 + r];
          __builtin_nontemporal_store(v * inv, &Out[(size_t)row * ldC + col]);
        }
      }
    }
  }
}

// Fused prep: [0,4096) cvt H, [4096,8192) cvt K, [8192,12288) transpose V.
// Transpose writes Vt in 16B chunks (128 threads x u32x4).
__global__ __launch_bounds__(256) void prep_kernel(
    const float* __restrict__ H, const float* __restrict__ Kin,
    const float* __restrict__ V, u16* __restrict__ Hb, u16* __restrict__ Kb,
    u16* __restrict__ Vt)
{
  int b = blockIdx.x;
  if (b < 8192) {
    const float* src = (b < 4096) ? H : Kin;
    u16* dst = (b < 4096) ? Hb : Kb;
    int i = (b & 4095) * 256 + threadIdx.x;
    f32x4 v = __builtin_nontemporal_load(&((const f32x4*)src)[i]);
    ushort4 o;
    o.x = f2bf(v.x); o.y = f2bf(v.y); o.z = f2bf(v.z); o.w = f2bf(v.w);
    ((ushort4*)dst)[i] = o;
  } else {
    __shared__ float tile[32][33];
    b -= 8192;
    int c0 = (b & 31) * 32;
    int r0 = (b >> 5) * 32;
    int tx = threadIdx.x & 31, ty = threadIdx.x >> 5;
    #pragma unroll
    for (int s = 0; s < 32; s += 8)
      tile[ty + s][tx] = __builtin_nontemporal_load(
          &V[(size_t)(r0 + ty + s) * 1024 + c0 + tx]);
    __syncthreads();
    if (threadIdx.x < 128) {
      int vr = threadIdx.x >> 2;           // 0..31 -> Vt row c0+vr
      int ch = threadIdx.x & 3;            // 16B chunk: r-offset ch*8
      u32x4 ov;
      #pragma unroll
      for (int p = 0; p < 4; ++p) {
        unsigned int lo = f2bf(tile[ch * 8 + p * 2][vr]);
        unsigned int hi = f2bf(tile[ch * 8 + p * 2 + 1][vr]);
        ov[p] = lo | (hi << 16);
      }
      *(u32x4*)&Vt[(size_t)(c0 + vr) * 4096 + r0 + ch * 8] = ov;
    }
  }
}

// softmax2: computes L1 locally (row exp-sum), then p = exp(exp(s)/L1 * mask)
// in-place over S (bf16), row sum -> L2. One block per row, no atomics.
__global__ __launch_bounds__(256) void softmax2_kernel(
    u16* __restrict__ S, const float* __restrict__ mask,
    float* __restrict__ L2, int M)
{
  int row = blockIdx.x;
  u16* srow = S + (size_t)row * M;
  const float* mrow = mask + (size_t)row * M;
  const int base = threadIdx.x * 16;       // M == blockDim.x*16

  u16 sl[16];
  *(uint4*)(sl)     = *(const uint4*)(srow + base);
  *(uint4*)(sl + 8) = *(const uint4*)(srow + base + 8);

  float e[16];
  float s1 = 0.f;
  #pragma unroll
  for (int j = 0; j < 16; ++j) { e[j] = __expf(bf2f(sl[j])); s1 += e[j]; }

  __shared__ float wred[8];
  #pragma unroll
  for (int m = 1; m < 64; m <<= 1) s1 += __shfl_xor(s1, m, 64);
  if ((threadIdx.x & 63) == 0) wred[threadIdx.x >> 6] = s1;
  __syncthreads();
  float inv = 1.0f / (wred[0] + wred[1] + wred[2] + wred[3]);

  float mv[16];
  #pragma unroll
  for (int q = 0; q < 4; ++q) {
    f32x4 m4 = __builtin_nontemporal_load((const f32x4*)(mrow + base + q * 4));
    mv[q * 4 + 0] = m4.x; mv[q * 4 + 1] = m4.y;
    mv[q * 4 + 2] = m4.z; mv[q * 4 + 3] = m4.w;
  }

  float lsum = 0.f;
  #pragma unroll
  for (int j = 0; j < 16; ++j) {
    float p = __expf(e[j] * inv * mv[j]);
    lsum += p;
    sl[j] = f2bf(p);
  }
  *(uint4*)(srow + base)     = *(uint4*)(sl);
  *(uint4*)(srow + base + 8) = *(uint4*)(sl + 8);

  #pragma unroll
  for (int m = 1; m < 64; m <<= 1) lsum += __shfl_xor(lsum, m, 64);
  if ((threadIdx.x & 63) == 0) wred[4 + (threadIdx.x >> 6)] = lsum;
  __syncthreads();
  if (threadIdx.x == 0) L2[row] = wred[4] + wred[5] + wred[6] + wred[7];
}

extern "C" void kernel_launch(void* const* d_in, const int* in_sizes, int n_in,
                              void* d_out, int out_size, void* d_ws, size_t ws_size,
                              hipStream_t stream) {
  const float* H    = (const float*)d_in[0];
  const float* Kin  = (const float*)d_in[1];
  const float* V    = (const float*)d_in[2];
  const float* mask = (const float*)d_in[3];
  float* out = (float*)d_out;

  const int N = 4096, M = 4096, D = 1024;

  char* ws = (char*)d_ws;
  u16*   Hb = (u16*)(ws);
  u16*   Kb = (u16*)(ws + (8ull << 20));
  u16*   Vt = (u16*)(ws + (16ull << 20));
  u16*   S  = (u16*)(ws + (24ull << 20));
  float* L2 = (float*)(ws + (56ull << 20));

  prep_kernel<<<dim3(12288), dim3(256), 0, stream>>>(H, Kin, V, Hb, Kb, Vt);

  gemm1_kernel<<<dim3(256), dim3(512), 0, stream>>>(Hb, Kb, S, D, D, M);

  softmax2_kernel<<<dim3(N), dim3(256), 0, stream>>>(S, mask, L2, M);

  gemm2_kernel<<<dim3(256), dim3(512), 0, stream>>>(S, Vt, out, L2, M, M, D);
}